// Round 2
// baseline (673.094 us; speedup 1.0000x reference)
//
#include <hip/hip_runtime.h>
#include <hip/hip_bf16.h>
#include <stdint.h>

#define LROW 25600
#define NCH 256
#define LN_EPS 1e-5f

typedef float f32x4 __attribute__((ext_vector_type(4)));
typedef __bf16 bf16x8 __attribute__((ext_vector_type(8)));
typedef __bf16 bf16x4 __attribute__((ext_vector_type(4)));
typedef uint32_t u32x2 __attribute__((ext_vector_type(2)));

__device__ __forceinline__ bf16x8 cvt8(f32x4 a, f32x4 b) {
  bf16x8 r;
  r[0] = (__bf16)a[0]; r[1] = (__bf16)a[1]; r[2] = (__bf16)a[2]; r[3] = (__bf16)a[3];
  r[4] = (__bf16)b[0]; r[5] = (__bf16)b[1]; r[6] = (__bf16)b[2]; r[7] = (__bf16)b[3];
  return r;
}

// raw barrier: drains LDS ops only, leaves prefetched global loads in flight
__device__ __forceinline__ void wg_bar() {
  asm volatile("s_waitcnt lgkmcnt(0)\n\ts_barrier" ::: "memory");
}

// ---------------------------------------------------------------------------
// Kernel A v2: per-batch Grams. 256 wgs = 8 b x (21 G + 11 Gkk slices).
// 1024 thr (16 waves, 4x4 wave grid, 64x64 wave tile -> acc 64 VGPR).
// bf16 reg-staged single-buffer LDS (32KB), XOR-swizzled, reg-prefetch.
// FULL: plain stores to per-slice partials (no atomics) + Gkk-wgs write kbf.
// ---------------------------------------------------------------------------
template <int FULL>
__global__ __launch_bounds__(1024, 4) void gram_k(
    const float* __restrict__ qg, const float* __restrict__ kg,
    float* __restrict__ Gd, float* __restrict__ Gkkd,
    float* __restrict__ sq, float* __restrict__ sk,
    __bf16* __restrict__ kbf) {
  __shared__ __align__(16) __bf16 lA[256 * 32];
  __shared__ __align__(16) __bf16 lB[256 * 32];
  const int bid = blockIdx.x;
  const int b = bid >> 5, s = bid & 31;
  const int mat = (s < 21) ? 0 : 1;
  const int idx = mat ? (s - 21) : s;
  const int parts = mat ? 11 : 21;
  const int c0 = (800 * idx) / parts, c1 = (800 * (idx + 1)) / parts;
  const int nc = c1 - c0;
  const int tid = threadIdx.x;
  const int w = tid >> 6, lane = tid & 63;
  const int wr = w >> 2, wc = w & 3;
  const int lr = lane & 15, g = lane >> 4;
  const float* Ag = (mat ? kg : qg) + (size_t)b * NCH * LROW;
  const float* Bg = kg + (size_t)b * NCH * LROW;

  // staging assignment: thread owns (row = tid>>2, 8-float unit u = tid&3)
  const int rowS = tid >> 2, uS = tid & 3;
  const int uSw = uS ^ ((rowS >> 1) & 3);
  const size_t gOff = (size_t)rowS * LROW + uS * 8;
  __bf16* ldsA_dst = lA + rowS * 32 + uSw * 8;
  __bf16* ldsB_dst = lB + rowS * 32 + uSw * 8;

  const f32x4 zero = {0.f, 0.f, 0.f, 0.f};
  f32x4 acc[4][4];
#pragma unroll
  for (int i = 0; i < 4; ++i)
#pragma unroll
    for (int j = 0; j < 4; ++j) acc[i][j] = zero;

  float rsum = 0.f;

  auto LOADG = [&](int c, f32x4* d) {
    const float* pa = Ag + gOff + (size_t)c * 32;
    d[0] = *(const f32x4*)pa;
    d[1] = *(const f32x4*)(pa + 4);
    if (mat == 0) {
      const float* pb = Bg + gOff + (size_t)c * 32;
      d[2] = *(const f32x4*)pb;
      d[3] = *(const f32x4*)(pb + 4);
    }
  };

  auto PROCESS = [&](int c, f32x4* d) {
#pragma unroll
    for (int e = 0; e < 4; ++e) rsum += d[0][e] + d[1][e];
    bf16x8 av = cvt8(d[0], d[1]);
    *(bf16x8*)ldsA_dst = av;
    if (mat == 0) {
      *(bf16x8*)ldsB_dst = cvt8(d[2], d[3]);
    } else if (FULL) {
      *(bf16x8*)(kbf + (size_t)(b * NCH + rowS) * LROW + (size_t)c * 32 + uS * 8) = av;
    }
    wg_bar();
    const __bf16* Bp = mat ? lA : lB;
    bf16x8 af[4];
#pragma unroll
    for (int i = 0; i < 4; ++i) {
      const int row = wr * 64 + i * 16 + lr;
      const int u = g ^ ((row >> 1) & 3);
      af[i] = *(const bf16x8*)(lA + row * 32 + u * 8);
    }
#pragma unroll
    for (int j = 0; j < 4; ++j) {
      const int row = wc * 64 + j * 16 + lr;
      const int u = g ^ ((row >> 1) & 3);
      bf16x8 bfj = *(const bf16x8*)(Bp + row * 32 + u * 8);
#pragma unroll
      for (int i = 0; i < 4; ++i)
        acc[i][j] = __builtin_amdgcn_mfma_f32_16x16x32_bf16(af[i], bfj, acc[i][j], 0, 0, 0);
    }
    wg_bar();
  };

  f32x4 bA[4], bB[4];
  LOADG(c0, bA);
  int cc = 0;
  for (; cc + 2 <= nc; cc += 2) {
    LOADG(c0 + cc + 1, bB);
    PROCESS(c0 + cc, bA);
    if (cc + 2 < nc) LOADG(c0 + cc + 2, bA);
    PROCESS(c0 + cc + 1, bB);
  }
  if (cc < nc) PROCESS(c0 + cc, bA);

  // row sums (exact fp32, from staged registers): G-wg sums q -> sq, Gkk sums k -> sk
  atomicAdd((mat ? sk : sq) + b * NCH + rowS, rsum);

  // epilogue
  if (FULL) {
    float* Gout = mat ? (Gkkd + ((size_t)b * 11 + idx) * 65536)
                      : (Gd + ((size_t)b * 21 + idx) * 65536);
#pragma unroll
    for (int i = 0; i < 4; ++i)
#pragma unroll
      for (int j = 0; j < 4; ++j) {
        const int col = wc * 64 + j * 16 + lr;
        const int row0 = wr * 64 + i * 16 + g * 4;
#pragma unroll
        for (int r = 0; r < 4; ++r)
          Gout[(size_t)(row0 + r) * NCH + col] = acc[i][j][r];
      }
  } else {
    float* Gout = (mat ? Gkkd : Gd) + (size_t)b * 65536;
#pragma unroll
    for (int i = 0; i < 4; ++i)
#pragma unroll
      for (int j = 0; j < 4; ++j) {
        const int col = wc * 64 + j * 16 + lr;
        const int row0 = wr * 64 + i * 16 + g * 4;
#pragma unroll
        for (int r = 0; r < 4; ++r)
          atomicAdd(&Gout[(size_t)(row0 + r) * NCH + col], acc[i][j][r]);
      }
  }
}

// ---------------------------------------------------------------------------
// reduce partial Grams: Gred = sum_21 Gp, Gkkred = sum_11 Gkkp
// ---------------------------------------------------------------------------
__global__ __launch_bounds__(256) void reduce_k(
    const float* __restrict__ Gp, const float* __restrict__ Gkkp,
    float* __restrict__ Gred, float* __restrict__ Gkkred) {
  const f32x4 zero = {0.f, 0.f, 0.f, 0.f};
  if (blockIdx.x < 512) {
    int f = (blockIdx.x * 256 + threadIdx.x) * 4;  // < 524288
    int b = f >> 16, r = f & 65535;
    f32x4 a = zero;
    for (int si = 0; si < 21; ++si)
      a += *(const f32x4*)(Gp + ((size_t)b * 21 + si) * 65536 + r);
    *(f32x4*)(Gred + f) = a;
  } else {
    int f = ((blockIdx.x - 512) * 256 + threadIdx.x) * 4;
    int b = f >> 16, r = f & 65535;
    f32x4 a = zero;
    for (int si = 0; si < 11; ++si)
      a += *(const f32x4*)(Gkkp + ((size_t)b * 11 + si) * 65536 + r);
    *(f32x4*)(Gkkred + f) = a;
  }
}

// ---------------------------------------------------------------------------
// Kernel B1: per (batch, head): scores -> softmax -> M = A*Wv_h, cvec = A*bv_h
// ---------------------------------------------------------------------------
__global__ __launch_bounds__(256) void attn_k(
    const float* __restrict__ G, const float* __restrict__ sq,
    const float* __restrict__ sk,
    const float* __restrict__ Wq, const float* __restrict__ bq,
    const float* __restrict__ Wk, const float* __restrict__ bk,
    const float* __restrict__ Wv, const float* __restrict__ bv,
    float* __restrict__ M, float* __restrict__ cvec) {
  __shared__ float Wql[32][257];
  __shared__ float Wkl[32][257];
  __shared__ float QGl[32][257];
  __shared__ float Sl[32][33];
  __shared__ float Al[32][33];
  __shared__ float ul[32], wl[32];
  const int b = blockIdx.x >> 3, h = blockIdx.x & 7;
  const int t = threadIdx.x;
  const float* Gb = G + (size_t)b * 65536;

  for (int i = 0; i < 32; ++i) {
    int idx = i * 256 + t;
    int d = idx >> 8, c = idx & 255;
    Wql[d][c] = Wq[(h * 32 + d) * 256 + c];
    Wkl[d][c] = Wk[(h * 32 + d) * 256 + c];
  }
  __syncthreads();
  {
    float a[32];
#pragma unroll
    for (int d = 0; d < 32; ++d) a[d] = 0.f;
    for (int c = 0; c < 256; ++c) {
      float gv = Gb[c * 256 + t];
#pragma unroll
      for (int d = 0; d < 32; ++d) a[d] += Wql[d][c] * gv;
    }
    for (int d = 0; d < 32; ++d) QGl[d][t] = a[d];
  }
  if (t < 32) {
    float u = 0.f, wv = 0.f;
    for (int c = 0; c < 256; ++c) {
      u += Wql[t][c] * sq[b * 256 + c];
      wv += Wkl[t][c] * sk[b * 256 + c];
    }
    ul[t] = u; wl[t] = wv;
  }
  __syncthreads();
  for (int i = 0; i < 4; ++i) {
    int idx = i * 256 + t;
    int d = idx >> 5, e = idx & 31;
    float sv = 0.f;
    for (int c = 0; c < 256; ++c) sv += QGl[d][c] * Wkl[e][c];
    float bqd = bq[h * 32 + d], bke = bk[h * 32 + e];
    Sl[d][e] = (sv + ul[d] * bke + bqd * wl[e] + 25600.f * bqd * bke) * (1.f / 16.f);
  }
  __syncthreads();
  if (t < 32) {
    float m = -1e30f;
    for (int e = 0; e < 32; ++e) m = fmaxf(m, Sl[t][e]);
    float ssum = 0.f;
    for (int e = 0; e < 32; ++e) { float p = __expf(Sl[t][e] - m); Al[t][e] = p; ssum += p; }
    float is = 1.f / ssum;
    for (int e = 0; e < 32; ++e) Al[t][e] *= is;
  }
  __syncthreads();
  {
    float a[32];
#pragma unroll
    for (int d = 0; d < 32; ++d) a[d] = 0.f;
    for (int e = 0; e < 32; ++e) {
      float wv = Wv[(h * 32 + e) * 256 + t];
#pragma unroll
      for (int d = 0; d < 32; ++d) a[d] += Al[d][e] * wv;
    }
    for (int d = 0; d < 32; ++d) M[((size_t)b * 256 + h * 32 + d) * 256 + t] = a[d];
  }
  if (t < 32) {
    float cv = 0.f;
    for (int e = 0; e < 32; ++e) cv += Al[t][e] * bv[h * 32 + e];
    cvec[b * 256 + h * 32 + t] = cv;
  }
}

// ---------------------------------------------------------------------------
// Kernel B2: LN stats via quadratic form  qf[c] = M[c,:] Gkk M[c,:]^T
// ---------------------------------------------------------------------------
__global__ __launch_bounds__(256) void stats_k(
    const float* __restrict__ Gkk, const float* __restrict__ M,
    const float* __restrict__ sk, const float* __restrict__ cvec,
    float* __restrict__ mu, float* __restrict__ inv) {
  __shared__ float Ml[32][257];
  __shared__ float Ql[32][257];
  const int b = blockIdx.x >> 3, cb = blockIdx.x & 7;
  const int t = threadIdx.x;
  const float* Gk = Gkk + (size_t)b * 65536;
  for (int i = 0; i < 32; ++i) {
    int idx = i * 256 + t;
    Ml[idx >> 8][idx & 255] = M[((size_t)b * 256 + cb * 32 + (idx >> 8)) * 256 + (idx & 255)];
  }
  __syncthreads();
  {
    float a[32];
#pragma unroll
    for (int c = 0; c < 32; ++c) a[c] = 0.f;
    for (int cc = 0; cc < 256; ++cc) {
      float gv = Gk[cc * 256 + t];
#pragma unroll
      for (int c = 0; c < 32; ++c) a[c] += Ml[c][cc] * gv;
    }
    for (int c = 0; c < 32; ++c) Ql[c][t] = a[c];
  }
  __syncthreads();
  if (t < 32) {
    float qf = 0.f, msk = 0.f;
    for (int j = 0; j < 256; ++j) {
      qf += Ql[t][j] * Ml[t][j];
      msk += Ml[t][j] * sk[b * 256 + j];
    }
    int c = cb * 32 + t;
    float cv = cvec[b * 256 + c];
    float muv = msk * (1.f / 25600.f) + cv;
    float sum2 = qf + 2.f * cv * msk + 25600.f * cv * cv;
    float var = sum2 * (1.f / 25600.f) - muv * muv;
    mu[b * 256 + c] = muv;
    inv[b * 256 + c] = rsqrtf(var + LN_EPS);
  }
}

// ---------------------------------------------------------------------------
// Kernel B3: P = (Wo o inv) M  (bf16), t1, wsum
// ---------------------------------------------------------------------------
__global__ __launch_bounds__(256) void pmat_k(
    const float* __restrict__ M, const float* __restrict__ Wo,
    const float* __restrict__ inv, const float* __restrict__ cvec,
    const float* __restrict__ mu, __bf16* __restrict__ Pb,
    float* __restrict__ t1, float* __restrict__ wsum) {
  __shared__ float Wol[32][257];
  __shared__ float invl[256];
  const int b = blockIdx.x >> 3, ob = blockIdx.x & 7;
  const int t = threadIdx.x;
  invl[t] = inv[b * 256 + t];
  __syncthreads();
  for (int i = 0; i < 32; ++i) {
    int idx = i * 256 + t;
    int o = idx >> 8, c = idx & 255;
    Wol[o][c] = Wo[(ob * 32 + o) * 256 + c] * invl[c];
  }
  __syncthreads();
  {
    float a[32];
#pragma unroll
    for (int o = 0; o < 32; ++o) a[o] = 0.f;
    for (int c = 0; c < 256; ++c) {
      float m = M[((size_t)b * 256 + c) * 256 + t];
#pragma unroll
      for (int o = 0; o < 32; ++o) a[o] += Wol[o][c] * m;
    }
    for (int o = 0; o < 32; ++o)
      Pb[((size_t)b * 256 + ob * 32 + o) * 256 + t] = (__bf16)a[o];
  }
  if (t < 32) {
    float s1 = 0.f, s2 = 0.f;
    for (int c = 0; c < 256; ++c) {
      s1 += Wol[t][c] * (cvec[b * 256 + c] - mu[b * 256 + c]);
      s2 += Wo[(ob * 32 + t) * 256 + c];
    }
    t1[b * 256 + ob * 32 + t] = s1;
    wsum[b * 256 + ob * 32 + t] = s2;
  }
}

// ---------------------------------------------------------------------------
// Kernel C v2 (FULL): out = gamma*(P kbf + t1) + beta*wsum + bo.
// 1600 wgs (b x 128-l tile), 512 thr, 8 waves (4r x 2c), 64KB LDS, 2 wg/CU.
// B-tile from bf16 kbf, transpose-staged into XOR-swizzled Bt[l][c].
// ---------------------------------------------------------------------------
__global__ __launch_bounds__(512, 4) void outb_k(
    const __bf16* __restrict__ kbf, const __bf16* __restrict__ Pb,
    const float* __restrict__ t1, const float* __restrict__ wsum,
    const float* __restrict__ bo, const float* __restrict__ gamma,
    const float* __restrict__ beta, float* __restrict__ out) {
  __shared__ __align__(16) __bf16 Bt[128 * 256];  // [l][c], XOR-swizzled, 64KB
  const int bid = blockIdx.x;
  const int b = bid / 200, lt = bid % 200, l0 = lt * 128;
  const int tid = threadIdx.x, w = tid >> 6, lane = tid & 63;
  const int wr = w >> 1, wc = w & 1;
  const int lr = lane & 15, g = lane >> 4;
  const __bf16* Kb = kbf + (size_t)b * NCH * LROW;

#pragma unroll
  for (int i = 0; i < 8; ++i) {
    const int cb = i * 32 + w * 4;
    const __bf16* src = Kb + (size_t)cb * LROW + l0 + lane * 2;
    uint32_t d0 = *(const uint32_t*)src;
    uint32_t d1 = *(const uint32_t*)(src + LROW);
    uint32_t d2 = *(const uint32_t*)(src + 2 * LROW);
    uint32_t d3 = *(const uint32_t*)(src + 3 * LROW);
    u32x2 lo, hi;
    lo[0] = (d0 & 0xffffu) | (d1 << 16);
    lo[1] = (d2 & 0xffffu) | (d3 << 16);
    hi[0] = (d0 >> 16) | (d1 & 0xffff0000u);
    hi[1] = (d2 >> 16) | (d3 & 0xffff0000u);
    const int unit = i * 4 + (w >> 1), sub = (w & 1) * 8;
    const int llo = lane * 2, lhi = llo + 1;
    *(u32x2*)((char*)Bt + llo * 512 + ((unit ^ (llo & 7)) << 4) + sub) = lo;
    *(u32x2*)((char*)Bt + lhi * 512 + ((unit ^ (lhi & 7)) << 4) + sub) = hi;
  }
  __syncthreads();

  const f32x4 zero = {0.f, 0.f, 0.f, 0.f};
  f32x4 acc[4][4];
#pragma unroll
  for (int i = 0; i < 4; ++i)
#pragma unroll
    for (int j = 0; j < 4; ++j) acc[i][j] = zero;

  const __bf16* Pbase = Pb + (size_t)b * 65536;
#pragma unroll
  for (int ks = 0; ks < 8; ++ks) {
    bf16x8 af[4];
#pragma unroll
    for (int i = 0; i < 4; ++i) {
      const int row = wr * 64 + i * 16 + lr;
      af[i] = *(const bf16x8*)(Pbase + (size_t)row * 256 + ks * 32 + g * 8);
    }
#pragma unroll
    for (int j = 0; j < 4; ++j) {
      const int col = wc * 64 + j * 16 + lr;
      const int unit = ks * 4 + g;
      bf16x8 bfj = *(const bf16x8*)((const char*)Bt + col * 512 + ((unit ^ (col & 7)) << 4));
#pragma unroll
      for (int i = 0; i < 4; ++i)
        acc[i][j] = __builtin_amdgcn_mfma_f32_16x16x32_bf16(af[i], bfj, acc[i][j], 0, 0, 0);
    }
  }

  float t1r[4][4], wsr[4][4], bor[4][4];
#pragma unroll
  for (int i = 0; i < 4; ++i)
#pragma unroll
    for (int r = 0; r < 4; ++r) {
      const int row = wr * 64 + i * 16 + g * 4 + r;
      t1r[i][r] = t1[b * 256 + row];
      wsr[i][r] = wsum[b * 256 + row];
      bor[i][r] = bo[row];
    }
#pragma unroll
  for (int j = 0; j < 4; ++j) {
    const int colg = l0 + wc * 64 + j * 16 + lr;
    const float gm = gamma[colg];
    const float bt = beta[colg];
#pragma unroll
    for (int i = 0; i < 4; ++i) {
      const int row0 = wr * 64 + i * 16 + g * 4;
#pragma unroll
      for (int r = 0; r < 4; ++r) {
        const int row = row0 + r;
        float v = gm * (acc[i][j][r] + t1r[i][r]) + bt * wsr[i][r] + bor[i][r];
        out[((size_t)b * 256 + row) * LROW + colg] = v;
      }
    }
  }
}

// ---------------------------------------------------------------------------
// Kernel C fallback (round-1, f32 key source) — used only if ws is too small
// ---------------------------------------------------------------------------
__global__ __launch_bounds__(512, 2) void out_f32_k(
    const float* __restrict__ key, const __bf16* __restrict__ Pb,
    const float* __restrict__ t1, const float* __restrict__ wsum,
    const float* __restrict__ bo, const float* __restrict__ gamma,
    const float* __restrict__ beta, float* __restrict__ out) {
  __shared__ __align__(16) __bf16 Bt[256 * 256];
  const int bid = blockIdx.x;
  const int b = bid / 100, tt = bid % 100;
  const int l0 = tt * 256;
  const int tid = threadIdx.x, w = tid >> 6, lane = tid & 63;
  const float* Kb = key + (size_t)b * NCH * LROW;

  for (int i = 0; i < 32; ++i) {
    int idx = i * 512 + tid;
    int l = idx & 255, cq = idx >> 8;
    float x0 = Kb[(size_t)(cq * 4 + 0) * LROW + l0 + l];
    float x1 = Kb[(size_t)(cq * 4 + 1) * LROW + l0 + l];
    float x2 = Kb[(size_t)(cq * 4 + 2) * LROW + l0 + l];
    float x3 = Kb[(size_t)(cq * 4 + 3) * LROW + l0 + l];
    bf16x4 hv;
    hv[0] = (__bf16)x0; hv[1] = (__bf16)x1; hv[2] = (__bf16)x2; hv[3] = (__bf16)x3;
    int unit = cq >> 1;
    int byteoff = l * 512 + (((unit ^ (l & 7))) << 4) + (cq & 1) * 8;
    *(bf16x4*)((char*)Bt + byteoff) = hv;
  }
  __syncthreads();

  const int rb = w >> 1, chh = w & 1;
  const f32x4 zero = {0.f, 0.f, 0.f, 0.f};
  f32x4 acc[2][4][4];
#pragma unroll
  for (int t = 0; t < 2; ++t)
#pragma unroll
    for (int i = 0; i < 4; ++i)
#pragma unroll
      for (int j = 0; j < 4; ++j) acc[t][i][j] = zero;

#pragma unroll
  for (int ks = 0; ks < 8; ++ks) {
    bf16x8 a[4];
#pragma unroll
    for (int i = 0; i < 4; ++i) {
      const int row = rb * 64 + i * 16 + (lane & 15);
      a[i] = *(const bf16x8*)(Pb + ((size_t)b * 256 + row) * 256 + ks * 32 + (lane >> 4) * 8);
    }
#pragma unroll
    for (int t = 0; t < 2; ++t) {
#pragma unroll
      for (int j = 0; j < 4; ++j) {
        const int col = chh * 128 + t * 64 + j * 16 + (lane & 15);
        const int unit = ks * 4 + (lane >> 4);
        const int byteoff = col * 512 + ((unit ^ (col & 7)) << 4);
        bf16x8 bfrag = *(const bf16x8*)((const char*)Bt + byteoff);
#pragma unroll
        for (int i = 0; i < 4; ++i)
          acc[t][i][j] = __builtin_amdgcn_mfma_f32_16x16x32_bf16(a[i], bfrag, acc[t][i][j], 0, 0, 0);
      }
    }
  }

  float t1r[4][4], wsr[4][4], bor[4][4];
#pragma unroll
  for (int i = 0; i < 4; ++i)
#pragma unroll
    for (int r = 0; r < 4; ++r) {
      const int row = rb * 64 + i * 16 + (lane >> 4) * 4 + r;
      t1r[i][r] = t1[b * 256 + row];
      wsr[i][r] = wsum[b * 256 + row];
      bor[i][r] = bo[row];
    }
#pragma unroll
  for (int t = 0; t < 2; ++t)
#pragma unroll
    for (int j = 0; j < 4; ++j) {
      const int col = chh * 128 + t * 64 + j * 16 + (lane & 15);
      const float gm = gamma[l0 + col];
      const float bt = beta[l0 + col];
#pragma unroll
      for (int i = 0; i < 4; ++i) {
        const int row0 = rb * 64 + i * 16 + (lane >> 4) * 4;
#pragma unroll
        for (int r = 0; r < 4; ++r) {
          const int row = row0 + r;
          float v = gm * (acc[t][i][j][r] + t1r[i][r]) + bt * wsr[i][r] + bor[i][r];
          out[((size_t)b * 256 + row) * LROW + l0 + col] = v;
        }
      }
    }
}

// ---------------------------------------------------------------------------
extern "C" void kernel_launch(void* const* d_in, const int* in_sizes, int n_in,
                              void* d_out, int out_size, void* d_ws, size_t ws_size,
                              hipStream_t stream) {
  const float* query = (const float*)d_in[0];
  const float* key   = (const float*)d_in[1];
  const float* Wq = (const float*)d_in[2];
  const float* bq = (const float*)d_in[3];
  const float* Wk = (const float*)d_in[4];
  const float* bk = (const float*)d_in[5];
  const float* Wv = (const float*)d_in[6];
  const float* bv = (const float*)d_in[7];
  const float* Wo = (const float*)d_in[8];
  const float* bo = (const float*)d_in[9];
  const float* gamma = (const float*)d_in[10];
  const float* beta  = (const float*)d_in[11];
  float* out = (float*)d_out;

  float* ws = (float*)d_ws;
  float* G    = ws;                  // 524288
  float* Gkk  = G + 524288;          // 524288
  float* sq   = Gkk + 524288;        // 2048
  float* sk   = sq + 2048;           // 2048
  float* M    = sk + 2048;           // 524288
  float* cvec = M + 524288;          // 2048
  float* mu   = cvec + 2048;         // 2048
  float* inv  = mu + 2048;           // 2048
  float* t1   = inv + 2048;          // 2048
  float* wsum = t1 + 2048;           // 2048
  __bf16* Pb  = (__bf16*)(wsum + 2048);       // 524288 bf16 = 262144 f
  __bf16* kbf = (__bf16*)(wsum + 2048 + 262144);  // 52428800 bf16 = 26214400 f
  float* Gp   = (float*)kbf + 13107200;       // wait: pointer math in floats below
  // recompute cleanly in float units:
  // base end (floats): 2*524288 + 4096 + 524288 + 5*2048 = 1587200
  // Pb:  1587200 .. +262144   -> 1849344
  // kbf: 1849344 .. +26214400 -> 28063744
  // Gp:  28063744 .. +11010048 -> 39073792
  // Gkkp:39073792 .. +5767168  -> 44840960
  Gp = ws + 28063744;
  float* Gkkp = ws + 39073792;
  const size_t need = (size_t)44840960 * 4;
  const bool full = ws_size >= need;

  if (full) {
    hipMemsetAsync(sq, 0, 4096 * sizeof(float), stream);  // sq+sk (atomic targets)
    gram_k<1><<<256, 1024, 0, stream>>>(query, key, Gp, Gkkp, sq, sk, kbf);
    reduce_k<<<1024, 256, 0, stream>>>(Gp, Gkkp, G, Gkk);
  } else {
    hipMemsetAsync(d_ws, 0, (size_t)1052672 * sizeof(float), stream);  // G,Gkk,sq,sk
    gram_k<0><<<256, 1024, 0, stream>>>(query, key, G, Gkk, sq, sk, nullptr);
  }
  attn_k<<<64, 256, 0, stream>>>(G, sq, sk, Wq, bq, Wk, bk, Wv, bv, M, cvec);
  stats_k<<<64, 256, 0, stream>>>(Gkk, M, sk, cvec, mu, inv);
  pmat_k<<<64, 256, 0, stream>>>(M, Wo, inv, cvec, mu, Pb, t1, wsum);
  if (full) {
    outb_k<<<1600, 512, 0, stream>>>(kbf, Pb, t1, wsum, bo, gamma, beta, out);
  } else {
    out_f32_k<<<800, 512, 0, stream>>>(key, Pb, t1, wsum, bo, gamma, beta, out);
  }
}